// Round 14
// baseline (1070.805 us; speedup 1.0000x reference)
//
#include <hip/hip_runtime.h>
#include <math.h>

#define D_MODEL 512
#define NHEAD   8
#define HEAD_DIM 64
#define BB      8
#define NN      1024
#define NS      1
#define TI      8
#define TJ      32
#define NT      (NN / TJ)
#define FIX_M   10.0f
#define GSTRIDE 40   // LDS row stride (shorts) for MFMA gemm tiles

typedef __attribute__((ext_vector_type(8))) short short8;
typedef __attribute__((ext_vector_type(4))) float floatx4;

// Branch-free gelu: erf via Abramowitz-Stegun 7.1.26 (|err| <= 1.5e-7).
__device__ __forceinline__ float gelu_fast(float x) {
    const float s = x * 0.70710678118654752f;
    const float u = fabsf(s);
    const float t = __builtin_amdgcn_rcpf(fmaf(0.3275911f, u, 1.0f));
    float p = fmaf(1.061405429f, t, -1.453152027f);
    p = fmaf(p, t, 1.421413741f);
    p = fmaf(p, t, -0.284496736f);
    p = fmaf(p, t, 0.254829592f);
    p = p * t;
    const float e = __expf(-u * u);
    float erf_u = fmaf(-p, e, 1.0f);
    erf_u = copysignf(erf_u, s);
    return 0.5f * x * (1.0f + erf_u);
}

__device__ __forceinline__ unsigned short f2bf(float f) {
    unsigned u = __float_as_uint(f);
    u = (u + 0x7fffu + ((u >> 16) & 1u)) >> 16;   // RNE
    return (unsigned short)u;
}

__device__ __forceinline__ uint2 pack4bf(float a, float b, float c, float d) {
    uint2 p;
    p.x = (unsigned)f2bf(a) | ((unsigned)f2bf(b) << 16);
    p.y = (unsigned)f2bf(c) | ((unsigned)f2bf(d) << 16);
    return p;
}

// ---------------- bf16 MFMA GEMM: qkv = x @ qkv_w^T, fused bf16 epilogue ----
__global__ __launch_bounds__(256)
void gemm_qkv_mfma(const float* __restrict__ A, const float* __restrict__ Bm,
                   unsigned short* __restrict__ Qb, unsigned short* __restrict__ Kb,
                   unsigned short* __restrict__ Vt) {
    __shared__ __align__(16) unsigned short As[128 * GSTRIDE];
    __shared__ __align__(16) unsigned short Bs[128 * GSTRIDE];
    const int tid = threadIdx.x;
    const int bm = blockIdx.y * 128;
    const int bn = blockIdx.x * 128;
    const int wv = tid >> 6, lane = tid & 63, quad = lane >> 4, ln = lane & 15;
    const int wm = (wv >> 1) * 64, wn = (wv & 1) * 64;

    floatx4 acc[4][4];
    #pragma unroll
    for (int i = 0; i < 4; ++i)
        #pragma unroll
        for (int j = 0; j < 4; ++j) acc[i][j] = (floatx4){0.f, 0.f, 0.f, 0.f};

    for (int k0 = 0; k0 < 512; k0 += 32) {
        __syncthreads();
        #pragma unroll
        for (int t = 0; t < 4; ++t) {
            const int c = tid + t * 256;
            const int row = c >> 3, kc = (c & 7) * 4;
            float4 v = *(const float4*)(A + (size_t)(bm + row) * 512 + k0 + kc);
            *(uint2*)&As[row * GSTRIDE + kc] = pack4bf(v.x, v.y, v.z, v.w);
            float4 w = *(const float4*)(Bm + (size_t)(bn + row) * 512 + k0 + kc);
            *(uint2*)&Bs[row * GSTRIDE + kc] = pack4bf(w.x, w.y, w.z, w.w);
        }
        __syncthreads();
        short8 af[4], bf[4];
        #pragma unroll
        for (int mb = 0; mb < 4; ++mb)
            af[mb] = *(const short8*)&As[(wm + mb * 16 + ln) * GSTRIDE + quad * 8];
        #pragma unroll
        for (int nb = 0; nb < 4; ++nb)
            bf[nb] = *(const short8*)&Bs[(wn + nb * 16 + ln) * GSTRIDE + quad * 8];
        #pragma unroll
        for (int mb = 0; mb < 4; ++mb)
            #pragma unroll
            for (int nb = 0; nb < 4; ++nb)
                acc[mb][nb] = __builtin_amdgcn_mfma_f32_16x16x32_bf16(af[mb], bf[nb], acc[mb][nb], 0, 0, 0);
    }

    #pragma unroll
    for (int nb = 0; nb < 4; ++nb) {
        const int n = bn + wn + nb * 16 + ln;
        #pragma unroll
        for (int mb = 0; mb < 4; ++mb) {
            const int m = bm + wm + mb * 16 + quad * 4;
            if (n < 512) {
                #pragma unroll
                for (int r = 0; r < 4; ++r)
                    Qb[(size_t)(m + r) * 512 + n] = f2bf(acc[mb][nb][r] * 0.125f);
            } else if (n < 1024) {
                #pragma unroll
                for (int r = 0; r < 4; ++r)
                    Kb[(size_t)(m + r) * 512 + (n - 512)] = f2bf(acc[mb][nb][r]);
            } else {
                const int bb = m >> 10, tok = m & 1023;
                *(uint2*)(Vt + ((size_t)bb * 512 + (n - 1024)) * NN + tok) =
                    pack4bf(acc[mb][nb][0], acc[mb][nb][1], acc[mb][nb][2], acc[mb][nb][3]);
            }
        }
    }
}

// ---------------- bf16 MFMA GEMM: out = attn_out(bf16) @ out_w^T + out_b ----
__global__ __launch_bounds__(256)
void gemm_out_mfma(const unsigned short* __restrict__ Ab, const float* __restrict__ Bm,
                   const float* __restrict__ bias, float* __restrict__ C) {
    __shared__ __align__(16) unsigned short As[128 * GSTRIDE];
    __shared__ __align__(16) unsigned short Bs[128 * GSTRIDE];
    const int tid = threadIdx.x;
    const int bm = blockIdx.y * 128;
    const int bn = blockIdx.x * 128;
    const int wv = tid >> 6, lane = tid & 63, quad = lane >> 4, ln = lane & 15;
    const int wm = (wv >> 1) * 64, wn = (wv & 1) * 64;

    floatx4 acc[4][4];
    #pragma unroll
    for (int i = 0; i < 4; ++i)
        #pragma unroll
        for (int j = 0; j < 4; ++j) acc[i][j] = (floatx4){0.f, 0.f, 0.f, 0.f};

    for (int k0 = 0; k0 < 512; k0 += 32) {
        __syncthreads();
        #pragma unroll
        for (int t = 0; t < 4; ++t) {
            const int c = tid + t * 256;
            const int row = c >> 3, kc = (c & 7) * 4;
            *(uint2*)&As[row * GSTRIDE + kc] =
                *(const uint2*)(Ab + (size_t)(bm + row) * 512 + k0 + kc);
            float4 w = *(const float4*)(Bm + (size_t)(bn + row) * 512 + k0 + kc);
            *(uint2*)&Bs[row * GSTRIDE + kc] = pack4bf(w.x, w.y, w.z, w.w);
        }
        __syncthreads();
        short8 af[4], bf[4];
        #pragma unroll
        for (int mb = 0; mb < 4; ++mb)
            af[mb] = *(const short8*)&As[(wm + mb * 16 + ln) * GSTRIDE + quad * 8];
        #pragma unroll
        for (int nb = 0; nb < 4; ++nb)
            bf[nb] = *(const short8*)&Bs[(wn + nb * 16 + ln) * GSTRIDE + quad * 8];
        #pragma unroll
        for (int mb = 0; mb < 4; ++mb)
            #pragma unroll
            for (int nb = 0; nb < 4; ++nb)
                acc[mb][nb] = __builtin_amdgcn_mfma_f32_16x16x32_bf16(af[mb], bf[nb], acc[mb][nb], 0, 0, 0);
    }

    #pragma unroll
    for (int nb = 0; nb < 4; ++nb) {
        const int n = bn + wn + nb * 16 + ln;
        const float bv = bias[n];
        #pragma unroll
        for (int mb = 0; mb < 4; ++mb) {
            const int m = bm + wm + mb * 16 + quad * 4;
            #pragma unroll
            for (int r = 0; r < 4; ++r)
                C[(size_t)(m + r) * 512 + n] = acc[mb][nb][r] + bv;
        }
    }
}

// ---------------- MFMA flash attention, TI=8 (grid 1024 = 4 blocks/CU) ------
// Block = (b, 8 queries, 8 heads); 256 thr = 4 waves, wave wv -> heads 2wv,2wv+1.
// MFMA tiles run 16 rows; rows 8-15 duplicate queries 0-7 (A loaded with ln&7,
// bias clamped row&7, epilogue stores quads 0-1 only). Math identical to R9.
#define BIAS_IDX(i, j, h) ((i) * 291 + (j) * 9 + (h))
__global__ __launch_bounds__(256, 4)
void attn_kernel(const unsigned short* __restrict__ Qb,
                 const unsigned short* __restrict__ Kb,
                 const unsigned short* __restrict__ Vt,
                 const float* __restrict__ coords,
                 const unsigned char* __restrict__ mask,
                 const float* __restrict__ w1, const float* __restrict__ b1,
                 const float* __restrict__ w2, const float* __restrict__ b2,
                 const float* __restrict__ coord_scales,
                 const float* __restrict__ alpha_p,
                 unsigned short* __restrict__ attn_out) {
    const int b   = blockIdx.y;
    const int i0  = blockIdx.x * TI;
    const int tid = threadIdx.x;
    const int wv  = tid >> 6;
    const int lane = tid & 63;
    const int quad = lane >> 4;
    const int ln   = lane & 15;
    const int qln  = ln & 7;         // query row for duplicated A rows
    const int h0   = wv * 2;

    __shared__ float bias_s[2][TI * 291 + 9];                   // 2 x 9.35 KB
    __shared__ __align__(16) unsigned short ps[NHEAD][16][40];  // 10 KB
    __shared__ float ci_s[TI][3];
    // total LDS ~28.8 KB -> 4 blocks/CU

    const float alpha = alpha_p[0];
    const float isx = 1.0f / coord_scales[0];
    const float isy = 1.0f / coord_scales[1];
    const float isz = 1.0f / coord_scales[2];

    if (tid < TI * 3)
        ci_s[tid / 3][tid % 3] =
            coords[((size_t)b * NN + i0 + tid / 3) * 3 + tid % 3] / coord_scales[tid % 3];

    // ---- per-lane MLP weight slice: units ku = quad*8+jj ----
    float4 w1r[8]; float b1r[8];
    #pragma unroll
    for (int jj = 0; jj < 8; ++jj) {
        w1r[jj] = *(const float4*)(w1 + (quad * 8 + jj) * 4);
        b1r[jj] = b1[quad * 8 + jj];
    }
    // w2 B-fragment: B[n=ln(head)][k=quad*8+jj] = alpha*w2, heads 8..15 -> 0
    short8 b2f;
    #pragma unroll
    for (int jj = 0; jj < 8; ++jj) {
        const float v = (ln < 8) ? alpha * w2[ln * 32 + quad * 8 + jj] : 0.0f;
        b2f[jj] = (short)f2bf(v);
    }
    const float ab2 = (ln < 8) ? alpha * b2[ln] : 0.0f;

    // Q A-fragments (bf16, pre-scaled by 0.125); rows 8-15 duplicate 0-7
    short8 qf[2][2];
    #pragma unroll
    for (int hh = 0; hh < 2; ++hh)
        #pragma unroll
        for (int kd = 0; kd < 2; ++kd)
            qf[hh][kd] = *(const short8*)(Qb + ((size_t)b * NN + i0 + qln) * 512
                                          + (h0 + hh) * 64 + kd * 32 + quad * 8);

    floatx4 oacc[2][4];
    #pragma unroll
    for (int hh = 0; hh < 2; ++hh)
        #pragma unroll
        for (int nd = 0; nd < 4; ++nd)
            oacc[hh][nd] = (floatx4){0.f, 0.f, 0.f, 0.f};
    float l_part[2][4];
    #pragma unroll
    for (int hh = 0; hh < 2; ++hh)
        #pragma unroll
        for (int r = 0; r < 4; ++r) l_part[hh][r] = 0.f;

    const unsigned char* maskp = mask + (size_t)b * NN;
    float cjx[2], cjy[2], cjz[2];

    #define LOAD_CJ(tt_) do { const int tt = (tt_);                               \
        if (tt < NT) {                                                            \
            const float* cp0 = coords + ((size_t)b * NN + tt * TJ + ln) * 3;      \
            cjx[0] = cp0[0] * isx; cjy[0] = cp0[1] * isy; cjz[0] = cp0[2] * isz;  \
            cjx[1] = cp0[48] * isx; cjy[1] = cp0[49] * isy; cjz[1] = cp0[50] * isz; \
        } } while (0)

    // MLP for tile tt -> bias_s[tt&1]; 2 i-groups x 2 j-halves per wave.
    #define MLP_TILE(tt_) do { const int tt = (tt_);                              \
        if (tt < NT) {                                                            \
            float* bout = bias_s[tt & 1];                                         \
            const int j0m = tt * TJ;                                              \
            _Pragma("unroll")                                                     \
            for (int g = 0; g < 2; ++g) {                                         \
                const int i = wv * 2 + g;                                         \
                const float cix = ci_s[i][0], ciy = ci_s[i][1], ciz = ci_s[i][2]; \
                const bool irow0 = (i0 + i < NS);                                 \
                _Pragma("unroll")                                                 \
                for (int jh = 0; jh < 2; ++jh) {                                  \
                    const float dx = cix - cjx[jh];                               \
                    const float dy = ciy - cjy[jh];                               \
                    const float dz = ciz - cjz[jh];                               \
                    const float dist = sqrtf(dx * dx + dy * dy + dz * dz);        \
                    short8 hf;                                                    \
                    _Pragma("unroll")                                             \
                    for (int jj = 0; jj < 8; ++jj) {                              \
                        const float4 wa = w1r[jj];                                \
                        float hu = fmaf(wa.x, dx, fmaf(wa.y, dy,                  \
                                   fmaf(wa.z, dz, fmaf(wa.w, dist, b1r[jj]))));   \
                        hu = gelu_fast(hu);                                       \
                        hf[jj] = (short)f2bf(hu);                                 \
                    }                                                             \
                    floatx4 D = __builtin_amdgcn_mfma_f32_16x16x32_bf16(          \
                        hf, b2f, (floatx4){0.f, 0.f, 0.f, 0.f}, 0, 0, 0);         \
                    if (ln < 8) {                                                 \
                        _Pragma("unroll")                                         \
                        for (int r = 0; r < 4; ++r) {                             \
                            const int jw = jh * 16 + quad * 4 + r;                \
                            const float val = (irow0 || (j0m + jw < NS))          \
                                              ? 0.0f : (D[r] + ab2);              \
                            bout[BIAS_IDX(i, jw, ln)] = val;                      \
                        }                                                         \
                    }                                                             \
                }                                                                 \
            }                                                                     \
        } } while (0)

    // ---- prologue ----
    __syncthreads();              // ci_s ready
    LOAD_CJ(0);
    MLP_TILE(0);
    __syncthreads();              // bias_s[0] ready

    for (int jt = 0; jt < NT; ++jt) {
        const int j0 = jt * TJ;
        const int pb = jt & 1;

        // ---- K/V/mask global loads for tile jt (fly under MLP) ----
        short8 kf[2][4], vf[2][4];
        #pragma unroll
        for (int hh = 0; hh < 2; ++hh) {
            const unsigned short* kbase = Kb + ((size_t)b * NN + j0) * 512 + (h0 + hh) * 64;
            kf[hh][0] = *(const short8*)(kbase + (size_t)ln * 512 + quad * 8);
            kf[hh][1] = *(const short8*)(kbase + (size_t)ln * 512 + 32 + quad * 8);
            kf[hh][2] = *(const short8*)(kbase + (size_t)(16 + ln) * 512 + quad * 8);
            kf[hh][3] = *(const short8*)(kbase + (size_t)(16 + ln) * 512 + 32 + quad * 8);
            const unsigned short* vbase = Vt + ((size_t)b * 512 + (h0 + hh) * 64) * NN + j0 + quad * 8;
            #pragma unroll
            for (int nd = 0; nd < 4; ++nd)
                vf[hh][nd] = *(const short8*)(vbase + (size_t)(nd * 16 + ln) * NN);
        }
        const unsigned char mm0 = maskp[j0 + ln];
        const unsigned char mm1 = maskp[j0 + 16 + ln];

        // ---- MLP for tile jt+1 -> bias_s[(jt+1)&1] ----
        LOAD_CJ(jt + 1);
        MLP_TILE(jt + 1);

        // ---- QK mfma + bias + exp -> ps (rows 8-15 are duplicates) ----
        #pragma unroll
        for (int hh = 0; hh < 2; ++hh) {
            const int h = h0 + hh;
            floatx4 s0 = (floatx4){0.f, 0.f, 0.f, 0.f};
            floatx4 s1 = (floatx4){0.f, 0.f, 0.f, 0.f};
            s0 = __builtin_amdgcn_mfma_f32_16x16x32_bf16(qf[hh][0], kf[hh][0], s0, 0, 0, 0);
            s0 = __builtin_amdgcn_mfma_f32_16x16x32_bf16(qf[hh][1], kf[hh][1], s0, 0, 0, 0);
            s1 = __builtin_amdgcn_mfma_f32_16x16x32_bf16(qf[hh][0], kf[hh][2], s1, 0, 0, 0);
            s1 = __builtin_amdgcn_mfma_f32_16x16x32_bf16(qf[hh][1], kf[hh][3], s1, 0, 0, 0);
            #pragma unroll
            for (int r = 0; r < 4; ++r) {
                const int row = quad * 4 + r;
                const int brow = row & 7;     // bias of the real (duplicated) query
                float v0 = s0[r] + bias_s[pb][BIAS_IDX(brow, ln, h)];
                float v1 = s1[r] + bias_s[pb][BIAS_IDX(brow, 16 + ln, h)];
                v0 = mm0 ? -1e30f : v0;
                v1 = mm1 ? -1e30f : v1;
                const float e0 = __expf(v0 - FIX_M);
                const float e1 = __expf(v1 - FIX_M);
                l_part[hh][r] += e0 + e1;
                ps[h][row][ln]      = f2bf(e0);
                ps[h][row][16 + ln] = f2bf(e1);
            }
        }

        // ---- PV mfma (ps read is within-wave) ----
        #pragma unroll
        for (int hh = 0; hh < 2; ++hh) {
            const int h = h0 + hh;
            short8 pa = *(const short8*)&ps[h][ln][quad * 8];
            #pragma unroll
            for (int nd = 0; nd < 4; ++nd)
                oacc[hh][nd] = __builtin_amdgcn_mfma_f32_16x16x32_bf16(pa, vf[hh][nd], oacc[hh][nd], 0, 0, 0);
        }

        __syncthreads();   // single barrier: bias_s[(jt+1)&1] ready
    }

    // epilogue: rows 0-7 only (quads 0-1); reduce l, O /= l, store bf16
    #pragma unroll
    for (int hh = 0; hh < 2; ++hh) {
        float rl[4];
        #pragma unroll
        for (int r = 0; r < 4; ++r) {
            float l = l_part[hh][r];
            l += __shfl_xor(l, 1, 64);
            l += __shfl_xor(l, 2, 64);
            l += __shfl_xor(l, 4, 64);
            l += __shfl_xor(l, 8, 64);
            rl[r] = 1.0f / l;
        }
        if (quad < 2) {
            #pragma unroll
            for (int nd = 0; nd < 4; ++nd)
                #pragma unroll
                for (int r = 0; r < 4; ++r)
                    attn_out[((size_t)b * NN + i0 + quad * 4 + r) * 512
                             + (h0 + hh) * 64 + nd * 16 + ln] = f2bf(oacc[hh][nd][r] * rl[r]);
        }
    }
    #undef LOAD_CJ
    #undef MLP_TILE
}

extern "C" void kernel_launch(void* const* d_in, const int* in_sizes, int n_in,
                              void* d_out, int out_size, void* d_ws, size_t ws_size,
                              hipStream_t stream) {
    const float* x        = (const float*)d_in[0];
    const float* coords   = (const float*)d_in[1];
    const unsigned char* kpm = (const unsigned char*)d_in[2];
    const float* qkv_w    = (const float*)d_in[3];
    const float* out_w    = (const float*)d_in[4];
    const float* out_b    = (const float*)d_in[5];
    const float* alpha    = (const float*)d_in[6];
    const float* w1       = (const float*)d_in[7];
    const float* b1       = (const float*)d_in[8];
    const float* w2       = (const float*)d_in[9];
    const float* b2       = (const float*)d_in[10];
    const float* cscales  = (const float*)d_in[11];
    float* out = (float*)d_out;

    const int M = BB * NN;
    // workspace: Qb/Kb/Vt/Ao all bf16 = 4 x 8.39 MB = 33.6 MB
    unsigned short* Qb = (unsigned short*)d_ws;
    unsigned short* Kb = Qb + (size_t)M * D_MODEL;
    unsigned short* Vt = Kb + (size_t)M * D_MODEL;
    unsigned short* Ao = Vt + (size_t)M * D_MODEL;

    {
        dim3 grid(3 * D_MODEL / 128, M / 128);
        gemm_qkv_mfma<<<grid, 256, 0, stream>>>(x, qkv_w, Qb, Kb, Vt);
    }
    {
        dim3 grid(NN / TI, BB);
        attn_kernel<<<grid, 256, 0, stream>>>(Qb, Kb, Vt, coords, kpm, w1, b1, w2, b2,
                                              cscales, alpha, Ao);
    }
    {
        dim3 grid(D_MODEL / 128, M / 128);
        gemm_out_mfma<<<grid, 256, 0, stream>>>(Ao, out_w, out_b, out);
    }
}

// Round 15
// 495.692 us; speedup vs baseline: 2.1602x; 2.1602x over previous
//
#include <hip/hip_runtime.h>
#include <math.h>

#define D_MODEL 512
#define NHEAD   8
#define HEAD_DIM 64
#define BB      8
#define NN      1024
#define NS      1
#define TI      8
#define TJ      32
#define NT      (NN / TJ)
#define FIX_M   10.0f
#define GSTRIDE 40   // LDS row stride (shorts) for MFMA gemm tiles

typedef __attribute__((ext_vector_type(8))) short short8;
typedef __attribute__((ext_vector_type(4))) float floatx4;

// Branch-free gelu: erf via Abramowitz-Stegun 7.1.26 (|err| <= 1.5e-7).
__device__ __forceinline__ float gelu_fast(float x) {
    const float s = x * 0.70710678118654752f;
    const float u = fabsf(s);
    const float t = __builtin_amdgcn_rcpf(fmaf(0.3275911f, u, 1.0f));
    float p = fmaf(1.061405429f, t, -1.453152027f);
    p = fmaf(p, t, 1.421413741f);
    p = fmaf(p, t, -0.284496736f);
    p = fmaf(p, t, 0.254829592f);
    p = p * t;
    const float e = __expf(-u * u);
    float erf_u = fmaf(-p, e, 1.0f);
    erf_u = copysignf(erf_u, s);
    return 0.5f * x * (1.0f + erf_u);
}

__device__ __forceinline__ unsigned short f2bf(float f) {
    unsigned u = __float_as_uint(f);
    u = (u + 0x7fffu + ((u >> 16) & 1u)) >> 16;   // RNE
    return (unsigned short)u;
}

__device__ __forceinline__ uint2 pack4bf(float a, float b, float c, float d) {
    uint2 p;
    p.x = (unsigned)f2bf(a) | ((unsigned)f2bf(b) << 16);
    p.y = (unsigned)f2bf(c) | ((unsigned)f2bf(d) << 16);
    return p;
}

// ---------------- bf16 MFMA GEMM: qkv = x @ qkv_w^T, fused bf16 epilogue ----
__global__ __launch_bounds__(256)
void gemm_qkv_mfma(const float* __restrict__ A, const float* __restrict__ Bm,
                   unsigned short* __restrict__ Qb, unsigned short* __restrict__ Kb,
                   unsigned short* __restrict__ Vt) {
    __shared__ __align__(16) unsigned short As[128 * GSTRIDE];
    __shared__ __align__(16) unsigned short Bs[128 * GSTRIDE];
    const int tid = threadIdx.x;
    const int bm = blockIdx.y * 128;
    const int bn = blockIdx.x * 128;
    const int wv = tid >> 6, lane = tid & 63, quad = lane >> 4, ln = lane & 15;
    const int wm = (wv >> 1) * 64, wn = (wv & 1) * 64;

    floatx4 acc[4][4];
    #pragma unroll
    for (int i = 0; i < 4; ++i)
        #pragma unroll
        for (int j = 0; j < 4; ++j) acc[i][j] = (floatx4){0.f, 0.f, 0.f, 0.f};

    for (int k0 = 0; k0 < 512; k0 += 32) {
        __syncthreads();
        #pragma unroll
        for (int t = 0; t < 4; ++t) {
            const int c = tid + t * 256;
            const int row = c >> 3, kc = (c & 7) * 4;
            float4 v = *(const float4*)(A + (size_t)(bm + row) * 512 + k0 + kc);
            *(uint2*)&As[row * GSTRIDE + kc] = pack4bf(v.x, v.y, v.z, v.w);
            float4 w = *(const float4*)(Bm + (size_t)(bn + row) * 512 + k0 + kc);
            *(uint2*)&Bs[row * GSTRIDE + kc] = pack4bf(w.x, w.y, w.z, w.w);
        }
        __syncthreads();
        short8 af[4], bf[4];
        #pragma unroll
        for (int mb = 0; mb < 4; ++mb)
            af[mb] = *(const short8*)&As[(wm + mb * 16 + ln) * GSTRIDE + quad * 8];
        #pragma unroll
        for (int nb = 0; nb < 4; ++nb)
            bf[nb] = *(const short8*)&Bs[(wn + nb * 16 + ln) * GSTRIDE + quad * 8];
        #pragma unroll
        for (int mb = 0; mb < 4; ++mb)
            #pragma unroll
            for (int nb = 0; nb < 4; ++nb)
                acc[mb][nb] = __builtin_amdgcn_mfma_f32_16x16x32_bf16(af[mb], bf[nb], acc[mb][nb], 0, 0, 0);
    }

    #pragma unroll
    for (int nb = 0; nb < 4; ++nb) {
        const int n = bn + wn + nb * 16 + ln;
        #pragma unroll
        for (int mb = 0; mb < 4; ++mb) {
            const int m = bm + wm + mb * 16 + quad * 4;
            if (n < 512) {
                #pragma unroll
                for (int r = 0; r < 4; ++r)
                    Qb[(size_t)(m + r) * 512 + n] = f2bf(acc[mb][nb][r] * 0.125f);
            } else if (n < 1024) {
                #pragma unroll
                for (int r = 0; r < 4; ++r)
                    Kb[(size_t)(m + r) * 512 + (n - 512)] = f2bf(acc[mb][nb][r]);
            } else {
                const int bb = m >> 10, tok = m & 1023;
                *(uint2*)(Vt + ((size_t)bb * 512 + (n - 1024)) * NN + tok) =
                    pack4bf(acc[mb][nb][0], acc[mb][nb][1], acc[mb][nb][2], acc[mb][nb][3]);
            }
        }
    }
}

// ---------------- bf16 MFMA GEMM: out = attn_out(bf16) @ out_w^T + out_b ----
__global__ __launch_bounds__(256)
void gemm_out_mfma(const unsigned short* __restrict__ Ab, const float* __restrict__ Bm,
                   const float* __restrict__ bias, float* __restrict__ C) {
    __shared__ __align__(16) unsigned short As[128 * GSTRIDE];
    __shared__ __align__(16) unsigned short Bs[128 * GSTRIDE];
    const int tid = threadIdx.x;
    const int bm = blockIdx.y * 128;
    const int bn = blockIdx.x * 128;
    const int wv = tid >> 6, lane = tid & 63, quad = lane >> 4, ln = lane & 15;
    const int wm = (wv >> 1) * 64, wn = (wv & 1) * 64;

    floatx4 acc[4][4];
    #pragma unroll
    for (int i = 0; i < 4; ++i)
        #pragma unroll
        for (int j = 0; j < 4; ++j) acc[i][j] = (floatx4){0.f, 0.f, 0.f, 0.f};

    for (int k0 = 0; k0 < 512; k0 += 32) {
        __syncthreads();
        #pragma unroll
        for (int t = 0; t < 4; ++t) {
            const int c = tid + t * 256;
            const int row = c >> 3, kc = (c & 7) * 4;
            *(uint2*)&As[row * GSTRIDE + kc] =
                *(const uint2*)(Ab + (size_t)(bm + row) * 512 + k0 + kc);
            float4 w = *(const float4*)(Bm + (size_t)(bn + row) * 512 + k0 + kc);
            *(uint2*)&Bs[row * GSTRIDE + kc] = pack4bf(w.x, w.y, w.z, w.w);
        }
        __syncthreads();
        short8 af[4], bf[4];
        #pragma unroll
        for (int mb = 0; mb < 4; ++mb)
            af[mb] = *(const short8*)&As[(wm + mb * 16 + ln) * GSTRIDE + quad * 8];
        #pragma unroll
        for (int nb = 0; nb < 4; ++nb)
            bf[nb] = *(const short8*)&Bs[(wn + nb * 16 + ln) * GSTRIDE + quad * 8];
        #pragma unroll
        for (int mb = 0; mb < 4; ++mb)
            #pragma unroll
            for (int nb = 0; nb < 4; ++nb)
                acc[mb][nb] = __builtin_amdgcn_mfma_f32_16x16x32_bf16(af[mb], bf[nb], acc[mb][nb], 0, 0, 0);
    }

    #pragma unroll
    for (int nb = 0; nb < 4; ++nb) {
        const int n = bn + wn + nb * 16 + ln;
        const float bv = bias[n];
        #pragma unroll
        for (int mb = 0; mb < 4; ++mb) {
            const int m = bm + wm + mb * 16 + quad * 4;
            #pragma unroll
            for (int r = 0; r < 4; ++r)
                C[(size_t)(m + r) * 512 + n] = acc[mb][nb][r] + bv;
        }
    }
}

// ---------------- MFMA flash attention, TI=8 (grid 1024 = 4 blocks/CU) ------
// Block = (b, 8 queries, 8 heads); 256 thr = 4 waves, wave wv -> heads 2wv,2wv+1.
// MFMA tiles run 16 rows; rows 8-15 duplicate queries 0-7 (A loaded with ln&7,
// bias clamped row&7, epilogue stores quads 0-1 only).
// __launch_bounds__(256,2): the only non-spilling setting (R11/R14: min-waves
// >=3 forces VGPR<=64 and catastrophic scratch traffic). Natural alloc ~120
// VGPR < 128 cliff -> 4 waves/SIMD; grid supplies 4 blocks/CU.
#define BIAS_IDX(i, j, h) ((i) * 291 + (j) * 9 + (h))
__global__ __launch_bounds__(256, 2)
void attn_kernel(const unsigned short* __restrict__ Qb,
                 const unsigned short* __restrict__ Kb,
                 const unsigned short* __restrict__ Vt,
                 const float* __restrict__ coords,
                 const unsigned char* __restrict__ mask,
                 const float* __restrict__ w1, const float* __restrict__ b1,
                 const float* __restrict__ w2, const float* __restrict__ b2,
                 const float* __restrict__ coord_scales,
                 const float* __restrict__ alpha_p,
                 unsigned short* __restrict__ attn_out) {
    const int b   = blockIdx.y;
    const int i0  = blockIdx.x * TI;
    const int tid = threadIdx.x;
    const int wv  = tid >> 6;
    const int lane = tid & 63;
    const int quad = lane >> 4;
    const int ln   = lane & 15;
    const int qln  = ln & 7;         // query row for duplicated A rows
    const int h0   = wv * 2;

    __shared__ float bias_s[2][TI * 291 + 9];                   // 2 x 9.35 KB
    __shared__ __align__(16) unsigned short ps[NHEAD][16][40];  // 10 KB
    __shared__ float ci_s[TI][3];
    // total LDS ~28.8 KB -> 4 blocks/CU fits (114 KB < 160 KB)

    const float alpha = alpha_p[0];
    const float isx = 1.0f / coord_scales[0];
    const float isy = 1.0f / coord_scales[1];
    const float isz = 1.0f / coord_scales[2];

    if (tid < TI * 3)
        ci_s[tid / 3][tid % 3] =
            coords[((size_t)b * NN + i0 + tid / 3) * 3 + tid % 3] / coord_scales[tid % 3];

    // ---- per-lane MLP weight slice: units ku = quad*8+jj ----
    float4 w1r[8]; float b1r[8];
    #pragma unroll
    for (int jj = 0; jj < 8; ++jj) {
        w1r[jj] = *(const float4*)(w1 + (quad * 8 + jj) * 4);
        b1r[jj] = b1[quad * 8 + jj];
    }
    // w2 B-fragment: B[n=ln(head)][k=quad*8+jj] = alpha*w2, heads 8..15 -> 0
    short8 b2f;
    #pragma unroll
    for (int jj = 0; jj < 8; ++jj) {
        const float v = (ln < 8) ? alpha * w2[ln * 32 + quad * 8 + jj] : 0.0f;
        b2f[jj] = (short)f2bf(v);
    }
    const float ab2 = (ln < 8) ? alpha * b2[ln] : 0.0f;

    // Q A-fragments (bf16, pre-scaled by 0.125); rows 8-15 duplicate 0-7
    short8 qf[2][2];
    #pragma unroll
    for (int hh = 0; hh < 2; ++hh)
        #pragma unroll
        for (int kd = 0; kd < 2; ++kd)
            qf[hh][kd] = *(const short8*)(Qb + ((size_t)b * NN + i0 + qln) * 512
                                          + (h0 + hh) * 64 + kd * 32 + quad * 8);

    floatx4 oacc[2][4];
    #pragma unroll
    for (int hh = 0; hh < 2; ++hh)
        #pragma unroll
        for (int nd = 0; nd < 4; ++nd)
            oacc[hh][nd] = (floatx4){0.f, 0.f, 0.f, 0.f};
    float l_part[2][4];
    #pragma unroll
    for (int hh = 0; hh < 2; ++hh)
        #pragma unroll
        for (int r = 0; r < 4; ++r) l_part[hh][r] = 0.f;

    const unsigned char* maskp = mask + (size_t)b * NN;
    float cjx[2], cjy[2], cjz[2];

    #define LOAD_CJ(tt_) do { const int tt = (tt_);                               \
        if (tt < NT) {                                                            \
            const float* cp0 = coords + ((size_t)b * NN + tt * TJ + ln) * 3;      \
            cjx[0] = cp0[0] * isx; cjy[0] = cp0[1] * isy; cjz[0] = cp0[2] * isz;  \
            cjx[1] = cp0[48] * isx; cjy[1] = cp0[49] * isy; cjz[1] = cp0[50] * isz; \
        } } while (0)

    // MLP for tile tt -> bias_s[tt&1]; 2 i-groups x 2 j-halves per wave.
    #define MLP_TILE(tt_) do { const int tt = (tt_);                              \
        if (tt < NT) {                                                            \
            float* bout = bias_s[tt & 1];                                         \
            const int j0m = tt * TJ;                                              \
            _Pragma("unroll")                                                     \
            for (int g = 0; g < 2; ++g) {                                         \
                const int i = wv * 2 + g;                                         \
                const float cix = ci_s[i][0], ciy = ci_s[i][1], ciz = ci_s[i][2]; \
                const bool irow0 = (i0 + i < NS);                                 \
                _Pragma("unroll")                                                 \
                for (int jh = 0; jh < 2; ++jh) {                                  \
                    const float dx = cix - cjx[jh];                               \
                    const float dy = ciy - cjy[jh];                               \
                    const float dz = ciz - cjz[jh];                               \
                    const float dist = sqrtf(dx * dx + dy * dy + dz * dz);        \
                    short8 hf;                                                    \
                    _Pragma("unroll")                                             \
                    for (int jj = 0; jj < 8; ++jj) {                              \
                        const float4 wa = w1r[jj];                                \
                        float hu = fmaf(wa.x, dx, fmaf(wa.y, dy,                  \
                                   fmaf(wa.z, dz, fmaf(wa.w, dist, b1r[jj]))));   \
                        hu = gelu_fast(hu);                                       \
                        hf[jj] = (short)f2bf(hu);                                 \
                    }                                                             \
                    floatx4 D = __builtin_amdgcn_mfma_f32_16x16x32_bf16(          \
                        hf, b2f, (floatx4){0.f, 0.f, 0.f, 0.f}, 0, 0, 0);         \
                    if (ln < 8) {                                                 \
                        _Pragma("unroll")                                         \
                        for (int r = 0; r < 4; ++r) {                             \
                            const int jw = jh * 16 + quad * 4 + r;                \
                            const float val = (irow0 || (j0m + jw < NS))          \
                                              ? 0.0f : (D[r] + ab2);              \
                            bout[BIAS_IDX(i, jw, ln)] = val;                      \
                        }                                                         \
                    }                                                             \
                }                                                                 \
            }                                                                     \
        } } while (0)

    // ---- prologue ----
    __syncthreads();              // ci_s ready
    LOAD_CJ(0);
    MLP_TILE(0);
    __syncthreads();              // bias_s[0] ready

    for (int jt = 0; jt < NT; ++jt) {
        const int j0 = jt * TJ;
        const int pb = jt & 1;

        // ---- K/V/mask global loads for tile jt (fly under MLP) ----
        short8 kf[2][4], vf[2][4];
        #pragma unroll
        for (int hh = 0; hh < 2; ++hh) {
            const unsigned short* kbase = Kb + ((size_t)b * NN + j0) * 512 + (h0 + hh) * 64;
            kf[hh][0] = *(const short8*)(kbase + (size_t)ln * 512 + quad * 8);
            kf[hh][1] = *(const short8*)(kbase + (size_t)ln * 512 + 32 + quad * 8);
            kf[hh][2] = *(const short8*)(kbase + (size_t)(16 + ln) * 512 + quad * 8);
            kf[hh][3] = *(const short8*)(kbase + (size_t)(16 + ln) * 512 + 32 + quad * 8);
            const unsigned short* vbase = Vt + ((size_t)b * 512 + (h0 + hh) * 64) * NN + j0 + quad * 8;
            #pragma unroll
            for (int nd = 0; nd < 4; ++nd)
                vf[hh][nd] = *(const short8*)(vbase + (size_t)(nd * 16 + ln) * NN);
        }
        const unsigned char mm0 = maskp[j0 + ln];
        const unsigned char mm1 = maskp[j0 + 16 + ln];

        // ---- MLP for tile jt+1 -> bias_s[(jt+1)&1] ----
        LOAD_CJ(jt + 1);
        MLP_TILE(jt + 1);

        // ---- QK mfma + bias + exp -> ps (rows 8-15 are duplicates) ----
        #pragma unroll
        for (int hh = 0; hh < 2; ++hh) {
            const int h = h0 + hh;
            floatx4 s0 = (floatx4){0.f, 0.f, 0.f, 0.f};
            floatx4 s1 = (floatx4){0.f, 0.f, 0.f, 0.f};
            s0 = __builtin_amdgcn_mfma_f32_16x16x32_bf16(qf[hh][0], kf[hh][0], s0, 0, 0, 0);
            s0 = __builtin_amdgcn_mfma_f32_16x16x32_bf16(qf[hh][1], kf[hh][1], s0, 0, 0, 0);
            s1 = __builtin_amdgcn_mfma_f32_16x16x32_bf16(qf[hh][0], kf[hh][2], s1, 0, 0, 0);
            s1 = __builtin_amdgcn_mfma_f32_16x16x32_bf16(qf[hh][1], kf[hh][3], s1, 0, 0, 0);
            #pragma unroll
            for (int r = 0; r < 4; ++r) {
                const int row = quad * 4 + r;
                const int brow = row & 7;     // bias of the real (duplicated) query
                float v0 = s0[r] + bias_s[pb][BIAS_IDX(brow, ln, h)];
                float v1 = s1[r] + bias_s[pb][BIAS_IDX(brow, 16 + ln, h)];
                v0 = mm0 ? -1e30f : v0;
                v1 = mm1 ? -1e30f : v1;
                const float e0 = __expf(v0 - FIX_M);
                const float e1 = __expf(v1 - FIX_M);
                l_part[hh][r] += e0 + e1;
                ps[h][row][ln]      = f2bf(e0);
                ps[h][row][16 + ln] = f2bf(e1);
            }
        }

        // ---- PV mfma (ps read is within-wave) ----
        #pragma unroll
        for (int hh = 0; hh < 2; ++hh) {
            const int h = h0 + hh;
            short8 pa = *(const short8*)&ps[h][ln][quad * 8];
            #pragma unroll
            for (int nd = 0; nd < 4; ++nd)
                oacc[hh][nd] = __builtin_amdgcn_mfma_f32_16x16x32_bf16(pa, vf[hh][nd], oacc[hh][nd], 0, 0, 0);
        }

        __syncthreads();   // single barrier: bias_s[(jt+1)&1] ready
    }

    // epilogue: rows 0-7 only (quads 0-1); reduce l, O /= l, store bf16
    #pragma unroll
    for (int hh = 0; hh < 2; ++hh) {
        float rl[4];
        #pragma unroll
        for (int r = 0; r < 4; ++r) {
            float l = l_part[hh][r];
            l += __shfl_xor(l, 1, 64);
            l += __shfl_xor(l, 2, 64);
            l += __shfl_xor(l, 4, 64);
            l += __shfl_xor(l, 8, 64);
            rl[r] = 1.0f / l;
        }
        if (quad < 2) {
            #pragma unroll
            for (int nd = 0; nd < 4; ++nd)
                #pragma unroll
                for (int r = 0; r < 4; ++r)
                    attn_out[((size_t)b * NN + i0 + quad * 4 + r) * 512
                             + (h0 + hh) * 64 + nd * 16 + ln] = f2bf(oacc[hh][nd][r] * rl[r]);
        }
    }
    #undef LOAD_CJ
    #undef MLP_TILE
}

extern "C" void kernel_launch(void* const* d_in, const int* in_sizes, int n_in,
                              void* d_out, int out_size, void* d_ws, size_t ws_size,
                              hipStream_t stream) {
    const float* x        = (const float*)d_in[0];
    const float* coords   = (const float*)d_in[1];
    const unsigned char* kpm = (const unsigned char*)d_in[2];
    const float* qkv_w    = (const float*)d_in[3];
    const float* out_w    = (const float*)d_in[4];
    const float* out_b    = (const float*)d_in[5];
    const float* alpha    = (const float*)d_in[6];
    const float* w1       = (const float*)d_in[7];
    const float* b1       = (const float*)d_in[8];
    const float* w2       = (const float*)d_in[9];
    const float* b2       = (const float*)d_in[10];
    const float* cscales  = (const float*)d_in[11];
    float* out = (float*)d_out;

    const int M = BB * NN;
    // workspace: Qb/Kb/Vt/Ao all bf16 = 4 x 8.39 MB = 33.6 MB
    unsigned short* Qb = (unsigned short*)d_ws;
    unsigned short* Kb = Qb + (size_t)M * D_MODEL;
    unsigned short* Vt = Kb + (size_t)M * D_MODEL;
    unsigned short* Ao = Vt + (size_t)M * D_MODEL;

    {
        dim3 grid(3 * D_MODEL / 128, M / 128);
        gemm_qkv_mfma<<<grid, 256, 0, stream>>>(x, qkv_w, Qb, Kb, Vt);
    }
    {
        dim3 grid(NN / TI, BB);
        attn_kernel<<<grid, 256, 0, stream>>>(Qb, Kb, Vt, coords, kpm, w1, b1, w2, b2,
                                              cscales, alpha, Ao);
    }
    {
        dim3 grid(D_MODEL / 128, M / 128);
        gemm_out_mfma<<<grid, 256, 0, stream>>>(Ao, out_w, out_b, out);
    }
}

// Round 17
// 361.314 us; speedup vs baseline: 2.9636x; 1.3719x over previous
//
#include <hip/hip_runtime.h>
#include <hip/hip_bf16.h>
#include <math.h>

#define D_MODEL 512
#define NHEAD   8
#define HEAD_DIM 64
#define BB      8
#define NN      1024
#define NS      1
#define TI      16
#define TJ      32
#define NT      (NN / TJ)
#define FIX_M   10.0f
#define GSTRIDE 40   // LDS row stride (shorts) for MFMA gemm tiles

typedef __attribute__((ext_vector_type(8))) short short8;
typedef __attribute__((ext_vector_type(4))) float floatx4;

// gelu, tanh form: 0.5x(1+tanh(0.79788(x+0.044715x^3))) = x*(1 - 1/(1+e^{2y}))
// 8 VALU ops, branch-free; |err vs erf-gelu| <= ~1e-3 absolute.
__device__ __forceinline__ float gelu_tanh(float x) {
    const float x2 = x * x;
    const float z  = x * fmaf(0.0713548162f, x2, 1.5957691216f);  // 2y
    const float e  = __expf(z);
    const float r  = __builtin_amdgcn_rcpf(1.0f + e);
    return fmaf(-x, r, x);
}

__device__ __forceinline__ unsigned short f2bf(float f) {
    unsigned u = __float_as_uint(f);
    u = (u + 0x7fffu + ((u >> 16) & 1u)) >> 16;   // RNE
    return (unsigned short)u;
}

__device__ __forceinline__ uint2 pack4bf(float a, float b, float c, float d) {
    uint2 p;
    p.x = (unsigned)f2bf(a) | ((unsigned)f2bf(b) << 16);
    p.y = (unsigned)f2bf(c) | ((unsigned)f2bf(d) << 16);
    return p;
}

// ---------------- bf16 MFMA GEMM: qkv = x @ qkv_w^T, fused bf16 epilogue ----
__global__ __launch_bounds__(256)
void gemm_qkv_mfma(const float* __restrict__ A, const float* __restrict__ Bm,
                   unsigned short* __restrict__ Qb, unsigned short* __restrict__ Kb,
                   unsigned short* __restrict__ Vt) {
    __shared__ __align__(16) unsigned short As[128 * GSTRIDE];
    __shared__ __align__(16) unsigned short Bs[128 * GSTRIDE];
    const int tid = threadIdx.x;
    const int bm = blockIdx.y * 128;
    const int bn = blockIdx.x * 128;
    const int wv = tid >> 6, lane = tid & 63, quad = lane >> 4, ln = lane & 15;
    const int wm = (wv >> 1) * 64, wn = (wv & 1) * 64;

    floatx4 acc[4][4];
    #pragma unroll
    for (int i = 0; i < 4; ++i)
        #pragma unroll
        for (int j = 0; j < 4; ++j) acc[i][j] = (floatx4){0.f, 0.f, 0.f, 0.f};

    for (int k0 = 0; k0 < 512; k0 += 32) {
        __syncthreads();
        #pragma unroll
        for (int t = 0; t < 4; ++t) {
            const int c = tid + t * 256;
            const int row = c >> 3, kc = (c & 7) * 4;
            float4 v = *(const float4*)(A + (size_t)(bm + row) * 512 + k0 + kc);
            *(uint2*)&As[row * GSTRIDE + kc] = pack4bf(v.x, v.y, v.z, v.w);
            float4 w = *(const float4*)(Bm + (size_t)(bn + row) * 512 + k0 + kc);
            *(uint2*)&Bs[row * GSTRIDE + kc] = pack4bf(w.x, w.y, w.z, w.w);
        }
        __syncthreads();
        short8 af[4], bf[4];
        #pragma unroll
        for (int mb = 0; mb < 4; ++mb)
            af[mb] = *(const short8*)&As[(wm + mb * 16 + ln) * GSTRIDE + quad * 8];
        #pragma unroll
        for (int nb = 0; nb < 4; ++nb)
            bf[nb] = *(const short8*)&Bs[(wn + nb * 16 + ln) * GSTRIDE + quad * 8];
        #pragma unroll
        for (int mb = 0; mb < 4; ++mb)
            #pragma unroll
            for (int nb = 0; nb < 4; ++nb)
                acc[mb][nb] = __builtin_amdgcn_mfma_f32_16x16x32_bf16(af[mb], bf[nb], acc[mb][nb], 0, 0, 0);
    }

    #pragma unroll
    for (int nb = 0; nb < 4; ++nb) {
        const int n = bn + wn + nb * 16 + ln;
        #pragma unroll
        for (int mb = 0; mb < 4; ++mb) {
            const int m = bm + wm + mb * 16 + quad * 4;
            if (n < 512) {
                #pragma unroll
                for (int r = 0; r < 4; ++r)
                    Qb[(size_t)(m + r) * 512 + n] = f2bf(acc[mb][nb][r] * 0.125f);
            } else if (n < 1024) {
                #pragma unroll
                for (int r = 0; r < 4; ++r)
                    Kb[(size_t)(m + r) * 512 + (n - 512)] = f2bf(acc[mb][nb][r]);
            } else {
                const int bb = m >> 10, tok = m & 1023;
                *(uint2*)(Vt + ((size_t)bb * 512 + (n - 1024)) * NN + tok) =
                    pack4bf(acc[mb][nb][0], acc[mb][nb][1], acc[mb][nb][2], acc[mb][nb][3]);
            }
        }
    }
}

// ---------------- bf16 MFMA GEMM: out = attn_out(bf16) @ out_w^T + out_b ----
__global__ __launch_bounds__(256)
void gemm_out_mfma(const unsigned short* __restrict__ Ab, const float* __restrict__ Bm,
                   const float* __restrict__ bias, float* __restrict__ C) {
    __shared__ __align__(16) unsigned short As[128 * GSTRIDE];
    __shared__ __align__(16) unsigned short Bs[128 * GSTRIDE];
    const int tid = threadIdx.x;
    const int bm = blockIdx.y * 128;
    const int bn = blockIdx.x * 128;
    const int wv = tid >> 6, lane = tid & 63, quad = lane >> 4, ln = lane & 15;
    const int wm = (wv >> 1) * 64, wn = (wv & 1) * 64;

    floatx4 acc[4][4];
    #pragma unroll
    for (int i = 0; i < 4; ++i)
        #pragma unroll
        for (int j = 0; j < 4; ++j) acc[i][j] = (floatx4){0.f, 0.f, 0.f, 0.f};

    for (int k0 = 0; k0 < 512; k0 += 32) {
        __syncthreads();
        #pragma unroll
        for (int t = 0; t < 4; ++t) {
            const int c = tid + t * 256;
            const int row = c >> 3, kc = (c & 7) * 4;
            *(uint2*)&As[row * GSTRIDE + kc] =
                *(const uint2*)(Ab + (size_t)(bm + row) * 512 + k0 + kc);
            float4 w = *(const float4*)(Bm + (size_t)(bn + row) * 512 + k0 + kc);
            *(uint2*)&Bs[row * GSTRIDE + kc] = pack4bf(w.x, w.y, w.z, w.w);
        }
        __syncthreads();
        short8 af[4], bf[4];
        #pragma unroll
        for (int mb = 0; mb < 4; ++mb)
            af[mb] = *(const short8*)&As[(wm + mb * 16 + ln) * GSTRIDE + quad * 8];
        #pragma unroll
        for (int nb = 0; nb < 4; ++nb)
            bf[nb] = *(const short8*)&Bs[(wn + nb * 16 + ln) * GSTRIDE + quad * 8];
        #pragma unroll
        for (int mb = 0; mb < 4; ++mb)
            #pragma unroll
            for (int nb = 0; nb < 4; ++nb)
                acc[mb][nb] = __builtin_amdgcn_mfma_f32_16x16x32_bf16(af[mb], bf[nb], acc[mb][nb], 0, 0, 0);
    }

    #pragma unroll
    for (int nb = 0; nb < 4; ++nb) {
        const int n = bn + wn + nb * 16 + ln;
        const float bv = bias[n];
        #pragma unroll
        for (int mb = 0; mb < 4; ++mb) {
            const int m = bm + wm + mb * 16 + quad * 4;
            #pragma unroll
            for (int r = 0; r < 4; ++r)
                C[(size_t)(m + r) * 512 + n] = acc[mb][nb][r] + bv;
        }
    }
}

// ---------------- MFMA flash attention (R16 + explicit LDS fence) ----------
// Block = (b, 16 queries, 8 heads); 256 thr = 4 waves, wave wv -> heads 2wv,2wv+1.
// Register-weight MLP, layer-2 as one mfma; fp32 bias_s double-buffered (only
// cross-wave handoff); ONE barrier per j-tile. Query coords in registers.
// The ps (P-matrix) LDS round-trip is within-wave but type-punned (u16 writes,
// short8 reads): an explicit s_waitcnt lgkmcnt(0) + compiler memory barrier
// between QK and PV pins both compiler and HW ordering (R16 tripwire failure
// attributed to a scheduler hoist of the punned ds_read past the ds_writes).
#define BIAS_IDX(i, j, h) ((i) * 291 + (j) * 9 + (h))
__global__ __launch_bounds__(256, 2)
void attn_kernel(const unsigned short* __restrict__ Qb,
                 const unsigned short* __restrict__ Kb,
                 const unsigned short* __restrict__ Vt,
                 const float* __restrict__ coords,
                 const unsigned char* __restrict__ mask,
                 const float* __restrict__ w1, const float* __restrict__ b1,
                 const float* __restrict__ w2, const float* __restrict__ b2,
                 const float* __restrict__ coord_scales,
                 const float* __restrict__ alpha_p,
                 unsigned short* __restrict__ attn_out) {
    const int b   = blockIdx.y;
    const int i0  = blockIdx.x * TI;
    const int tid = threadIdx.x;
    const int wv  = tid >> 6;
    const int lane = tid & 63;
    const int quad = lane >> 4;
    const int ln   = lane & 15;
    const int h0   = wv * 2;

    __shared__ float bias_s[2][TI * 291 + 9];                   // 2 x 18.65 KB
    __shared__ __align__(16) unsigned short ps[NHEAD][TI][40];  // 10 KB

    const float alpha = alpha_p[0];
    const float isx = 1.0f / coord_scales[0];
    const float isy = 1.0f / coord_scales[1];
    const float isz = 1.0f / coord_scales[2];

    // this wave's 4 query coords in registers (loop-invariant)
    float cir[4][3];
    #pragma unroll
    for (int g = 0; g < 4; ++g) {
        const float* cp = coords + ((size_t)b * NN + i0 + wv * 4 + g) * 3;
        cir[g][0] = cp[0] * isx; cir[g][1] = cp[1] * isy; cir[g][2] = cp[2] * isz;
    }

    // ---- per-lane MLP weight slice: units ku = quad*8+jj ----
    float4 w1r[8]; float b1r[8];
    #pragma unroll
    for (int jj = 0; jj < 8; ++jj) {
        w1r[jj] = *(const float4*)(w1 + (quad * 8 + jj) * 4);
        b1r[jj] = b1[quad * 8 + jj];
    }
    // w2 B-fragment: B[n=ln(head)][k=quad*8+jj] = alpha*w2, heads 8..15 -> 0
    short8 b2f;
    #pragma unroll
    for (int jj = 0; jj < 8; ++jj) {
        const float v = (ln < 8) ? alpha * w2[ln * 32 + quad * 8 + jj] : 0.0f;
        b2f[jj] = (short)f2bf(v);
    }
    const float ab2 = (ln < 8) ? alpha * b2[ln] : 0.0f;

    // Q A-fragments (bf16, pre-scaled by 0.125)
    short8 qf[2][2];
    #pragma unroll
    for (int hh = 0; hh < 2; ++hh)
        #pragma unroll
        for (int kd = 0; kd < 2; ++kd)
            qf[hh][kd] = *(const short8*)(Qb + ((size_t)b * NN + i0 + ln) * 512
                                          + (h0 + hh) * 64 + kd * 32 + quad * 8);

    floatx4 oacc[2][4];
    #pragma unroll
    for (int hh = 0; hh < 2; ++hh)
        #pragma unroll
        for (int nd = 0; nd < 4; ++nd)
            oacc[hh][nd] = (floatx4){0.f, 0.f, 0.f, 0.f};
    float l_part[2][4];
    #pragma unroll
    for (int hh = 0; hh < 2; ++hh)
        #pragma unroll
        for (int r = 0; r < 4; ++r) l_part[hh][r] = 0.f;

    const unsigned char* maskp = mask + (size_t)b * NN;
    float cjx[2], cjy[2], cjz[2];

    #define LOAD_CJ(tt_) do { const int tt = (tt_);                               \
        if (tt < NT) {                                                            \
            const float* cp0 = coords + ((size_t)b * NN + tt * TJ + ln) * 3;      \
            cjx[0] = cp0[0] * isx; cjy[0] = cp0[1] * isy; cjz[0] = cp0[2] * isz;  \
            cjx[1] = cp0[48] * isx; cjy[1] = cp0[49] * isy; cjz[1] = cp0[50] * isz; \
        } } while (0)

    // MLP for tile tt -> bias_s[tt&1]; 4 i-groups x 2 j-halves per wave.
    #define MLP_TILE(tt_) do { const int tt = (tt_);                              \
        if (tt < NT) {                                                            \
            float* bout = bias_s[tt & 1];                                         \
            const int j0m = tt * TJ;                                              \
            _Pragma("unroll")                                                     \
            for (int g = 0; g < 4; ++g) {                                         \
                const int i = wv * 4 + g;                                         \
                const float cix = cir[g][0], ciy = cir[g][1], ciz = cir[g][2];    \
                const bool irow0 = (i0 + i < NS);                                 \
                _Pragma("unroll")                                                 \
                for (int jh = 0; jh < 2; ++jh) {                                  \
                    const float dx = cix - cjx[jh];                               \
                    const float dy = ciy - cjy[jh];                               \
                    const float dz = ciz - cjz[jh];                               \
                    const float dist = sqrtf(dx * dx + dy * dy + dz * dz);        \
                    float hu[8];                                                  \
                    _Pragma("unroll")                                             \
                    for (int jj = 0; jj < 8; ++jj) {                              \
                        const float4 wa = w1r[jj];                                \
                        float t0 = fmaf(wa.x, dx, fmaf(wa.y, dy,                  \
                                   fmaf(wa.z, dz, fmaf(wa.w, dist, b1r[jj]))));   \
                        hu[jj] = gelu_tanh(t0);                                   \
                    }                                                             \
                    union { short8 s8; unsigned u4[4]; } H;                       \
                    _Pragma("unroll")                                             \
                    for (int k = 0; k < 4; ++k) {                                 \
                        __hip_bfloat162 t2 = __float22bfloat162_rn(               \
                            make_float2(hu[2 * k], hu[2 * k + 1]));               \
                        H.u4[k] = *(unsigned*)&t2;                                \
                    }                                                             \
                    floatx4 D = __builtin_amdgcn_mfma_f32_16x16x32_bf16(          \
                        H.s8, b2f, (floatx4){0.f, 0.f, 0.f, 0.f}, 0, 0, 0);       \
                    if (ln < 8) {                                                 \
                        _Pragma("unroll")                                         \
                        for (int r = 0; r < 4; ++r) {                             \
                            const int jw = jh * 16 + quad * 4 + r;                \
                            const float val = (irow0 || (j0m + jw < NS))          \
                                              ? 0.0f : (D[r] + ab2);              \
                            bout[BIAS_IDX(i, jw, ln)] = val;                      \
                        }                                                         \
                    }                                                             \
                }                                                                 \
            }                                                                     \
        } } while (0)

    // ---- prologue ----
    LOAD_CJ(0);
    MLP_TILE(0);
    __syncthreads();              // bias_s[0] ready

    for (int jt = 0; jt < NT; ++jt) {
        const int j0 = jt * TJ;
        const int pb = jt & 1;

        // ---- K/V/mask global loads for tile jt (fly under MLP) ----
        short8 kf[2][4], vf[2][4];
        #pragma unroll
        for (int hh = 0; hh < 2; ++hh) {
            const unsigned short* kbase = Kb + ((size_t)b * NN + j0) * 512 + (h0 + hh) * 64;
            kf[hh][0] = *(const short8*)(kbase + (size_t)ln * 512 + quad * 8);
            kf[hh][1] = *(const short8*)(kbase + (size_t)ln * 512 + 32 + quad * 8);
            kf[hh][2] = *(const short8*)(kbase + (size_t)(16 + ln) * 512 + quad * 8);
            kf[hh][3] = *(const short8*)(kbase + (size_t)(16 + ln) * 512 + 32 + quad * 8);
            const unsigned short* vbase = Vt + ((size_t)b * 512 + (h0 + hh) * 64) * NN + j0 + quad * 8;
            #pragma unroll
            for (int nd = 0; nd < 4; ++nd)
                vf[hh][nd] = *(const short8*)(vbase + (size_t)(nd * 16 + ln) * NN);
        }
        const unsigned char mm0 = maskp[j0 + ln];
        const unsigned char mm1 = maskp[j0 + 16 + ln];

        // ---- MLP for tile jt+1 -> bias_s[(jt+1)&1] ----
        LOAD_CJ(jt + 1);
        MLP_TILE(jt + 1);

        // ---- QK mfma + bias + exp -> ps (reads bias_s[jt&1]; within-wave ps) ----
        #pragma unroll
        for (int hh = 0; hh < 2; ++hh) {
            const int h = h0 + hh;
            floatx4 s0 = (floatx4){0.f, 0.f, 0.f, 0.f};
            floatx4 s1 = (floatx4){0.f, 0.f, 0.f, 0.f};
            s0 = __builtin_amdgcn_mfma_f32_16x16x32_bf16(qf[hh][0], kf[hh][0], s0, 0, 0, 0);
            s0 = __builtin_amdgcn_mfma_f32_16x16x32_bf16(qf[hh][1], kf[hh][1], s0, 0, 0, 0);
            s1 = __builtin_amdgcn_mfma_f32_16x16x32_bf16(qf[hh][0], kf[hh][2], s1, 0, 0, 0);
            s1 = __builtin_amdgcn_mfma_f32_16x16x32_bf16(qf[hh][1], kf[hh][3], s1, 0, 0, 0);
            #pragma unroll
            for (int r = 0; r < 4; ++r) {
                const int row = quad * 4 + r;
                float v0 = s0[r] + bias_s[pb][BIAS_IDX(row, ln, h)];
                float v1 = s1[r] + bias_s[pb][BIAS_IDX(row, 16 + ln, h)];
                v0 = mm0 ? -1e30f : v0;
                v1 = mm1 ? -1e30f : v1;
                const float e0 = __expf(v0 - FIX_M);
                const float e1 = __expf(v1 - FIX_M);
                l_part[hh][r] += e0 + e1;
                ps[h][row][ln]      = f2bf(e0);
                ps[h][row][16 + ln] = f2bf(e1);
            }
        }

        // ---- explicit fence: all ps LDS writes drained & compiler-ordered ----
        asm volatile("s_waitcnt lgkmcnt(0)" ::: "memory");

        // ---- PV mfma (ps read is within-wave, now explicitly fenced) ----
        #pragma unroll
        for (int hh = 0; hh < 2; ++hh) {
            const int h = h0 + hh;
            short8 pa = *(const short8*)&ps[h][ln][quad * 8];
            #pragma unroll
            for (int nd = 0; nd < 4; ++nd)
                oacc[hh][nd] = __builtin_amdgcn_mfma_f32_16x16x32_bf16(pa, vf[hh][nd], oacc[hh][nd], 0, 0, 0);
        }

        __syncthreads();   // single barrier: bias_s[(jt+1)&1] ready
    }

    // epilogue: reduce l over 16 lanes per row, O /= l, store bf16
    #pragma unroll
    for (int hh = 0; hh < 2; ++hh) {
        float rl[4];
        #pragma unroll
        for (int r = 0; r < 4; ++r) {
            float l = l_part[hh][r];
            l += __shfl_xor(l, 1, 64);
            l += __shfl_xor(l, 2, 64);
            l += __shfl_xor(l, 4, 64);
            l += __shfl_xor(l, 8, 64);
            rl[r] = 1.0f / l;
        }
        #pragma unroll
        for (int nd = 0; nd < 4; ++nd)
            #pragma unroll
            for (int r = 0; r < 4; ++r)
                attn_out[((size_t)b * NN + i0 + quad * 4 + r) * 512
                         + (h0 + hh) * 64 + nd * 16 + ln] = f2bf(oacc[hh][nd][r] * rl[r]);
    }
    #undef LOAD_CJ
    #undef MLP_TILE
}

extern "C" void kernel_launch(void* const* d_in, const int* in_sizes, int n_in,
                              void* d_out, int out_size, void* d_ws, size_t ws_size,
                              hipStream_t stream) {
    const float* x        = (const float*)d_in[0];
    const float* coords   = (const float*)d_in[1];
    const unsigned char* kpm = (const unsigned char*)d_in[2];
    const float* qkv_w    = (const float*)d_in[3];
    const float* out_w    = (const float*)d_in[4];
    const float* out_b    = (const float*)d_in[5];
    const float* alpha    = (const float*)d_in[6];
    const float* w1       = (const float*)d_in[7];
    const float* b1       = (const float*)d_in[8];
    const float* w2       = (const float*)d_in[9];
    const float* b2       = (const float*)d_in[10];
    const float* cscales  = (const float*)d_in[11];
    float* out = (float*)d_out;

    const int M = BB * NN;
    // workspace: Qb/Kb/Vt/Ao all bf16 = 4 x 8.39 MB = 33.6 MB
    unsigned short* Qb = (unsigned short*)d_ws;
    unsigned short* Kb = Qb + (size_t)M * D_MODEL;
    unsigned short* Vt = Kb + (size_t)M * D_MODEL;
    unsigned short* Ao = Vt + (size_t)M * D_MODEL;

    {
        dim3 grid(3 * D_MODEL / 128, M / 128);
        gemm_qkv_mfma<<<grid, 256, 0, stream>>>(x, qkv_w, Qb, Kb, Vt);
    }
    {
        dim3 grid(NN / TI, BB);
        attn_kernel<<<grid, 256, 0, stream>>>(Qb, Kb, Vt, coords, kpm, w1, b1, w2, b2,
                                              cscales, alpha, Ao);
    }
    {
        dim3 grid(D_MODEL / 128, M / 128);
        gemm_out_mfma<<<grid, 256, 0, stream>>>(Ao, out_w, out_b, out);
    }
}